// Round 1
// baseline (768.114 us; speedup 1.0000x reference)
//
#include <hip/hip_runtime.h>
#include <hip/hip_bf16.h>

#define NTOK 2048   // B*S
#define HD   1024
#define FD   3584
#define NE   8

#define BM 128
#define BN 128
#define BK 64
#define LDK 72      // 64 + 8 bf16 pad -> 144B row stride, kills bank conflicts on b128 reads

typedef __attribute__((ext_vector_type(8))) short short8;
typedef __attribute__((ext_vector_type(4))) float f32x4;

__device__ __forceinline__ unsigned short f2bf(float f) {
    __hip_bfloat16 h = __float2bfloat16(f);
    union { __hip_bfloat16 h; unsigned short u; } c; c.h = h;
    return c.u;
}

// ---------------- router: fp32 logits, softmax, top-2, renorm ----------------
__global__ void k_router(const float* __restrict__ x, const float* __restrict__ gw,
                         int* __restrict__ sel, float* __restrict__ selw,
                         int* __restrict__ counts) {
    int token = blockIdx.x * 4 + (threadIdx.x >> 6);
    int lane  = threadIdx.x & 63;
    if (token >= NTOK) return;
    const float* xr = x + (size_t)token * HD;
    float acc[NE];
#pragma unroll
    for (int e = 0; e < NE; e++) acc[e] = 0.f;
    for (int h = lane; h < HD; h += 64) {
        float xv = xr[h];
        const float4* g = (const float4*)(gw + (size_t)h * NE);
        float4 g0 = g[0], g1 = g[1];
        acc[0] += xv * g0.x; acc[1] += xv * g0.y; acc[2] += xv * g0.z; acc[3] += xv * g0.w;
        acc[4] += xv * g1.x; acc[5] += xv * g1.y; acc[6] += xv * g1.z; acc[7] += xv * g1.w;
    }
#pragma unroll
    for (int e = 0; e < NE; e++) {
#pragma unroll
        for (int off = 32; off >= 1; off >>= 1) acc[e] += __shfl_xor(acc[e], off, 64);
    }
    if (lane == 0) {
        float m = acc[0];
#pragma unroll
        for (int e = 1; e < NE; e++) m = fmaxf(m, acc[e]);
        float z[NE];
#pragma unroll
        for (int e = 0; e < NE; e++) z[e] = expf(acc[e] - m);
        // top-2 (strict >, ascending scan == first-index tie-break like lax.top_k)
        int e0 = 0; float z0 = z[0];
#pragma unroll
        for (int e = 1; e < NE; e++) if (z[e] > z0) { z0 = z[e]; e0 = e; }
        int e1 = -1; float z1 = -1.f;
#pragma unroll
        for (int e = 0; e < NE; e++) if (e != e0 && z[e] > z1) { z1 = z[e]; e1 = e; }
        float s = z0 + z1;
        sel[token * 2 + 0] = e0; sel[token * 2 + 1] = e1;
        selw[token * 2 + 0] = z0 / s; selw[token * 2 + 1] = z1 / s;
        atomicAdd(&counts[e0], 1);
        atomicAdd(&counts[e1], 1);
    }
}

__global__ void k_scan(const int* __restrict__ counts, int* __restrict__ basep,
                       int* __restrict__ fillc) {
    if (threadIdx.x == 0 && blockIdx.x == 0) {
        int b = 0;
        for (int e = 0; e < NE; e++) { basep[e] = b; b += counts[e]; fillc[e] = 0; }
    }
}

__global__ void k_fill(const int* __restrict__ sel, const float* __restrict__ selw,
                       const int* __restrict__ basep, int* __restrict__ fillc,
                       int* __restrict__ rowmap, int* __restrict__ rowk,
                       float* __restrict__ roww) {
    int n = blockIdx.x * blockDim.x + threadIdx.x;
    if (n >= NTOK) return;
#pragma unroll
    for (int k = 0; k < 2; k++) {
        int e = sel[n * 2 + k];
        int p = atomicAdd(&fillc[e], 1);
        int g = basep[e] + p;
        rowmap[g] = n; rowk[g] = k; roww[g] = selw[n * 2 + k];
    }
}

// ---------------- x -> bf16 ----------------
__global__ void k_cvt(const float* __restrict__ x, unsigned short* __restrict__ xb) {
    size_t i = ((size_t)blockIdx.x * blockDim.x + threadIdx.x) * 8;
    float4 a = *(const float4*)(x + i);
    float4 b = *(const float4*)(x + i + 4);
    unsigned short p[8] = { f2bf(a.x), f2bf(a.y), f2bf(a.z), f2bf(a.w),
                            f2bf(b.x), f2bf(b.y), f2bf(b.z), f2bf(b.w) };
    *(uint4*)(xb + i) = *(uint4*)p;
}

// ---------------- GEMM1: act = silu(X@W1) * (X@W3), grouped by expert ----------------
__global__ __launch_bounds__(256, 2) void k_gemm1(
    const unsigned short* __restrict__ xb,
    const float* __restrict__ w1, const float* __restrict__ w3,
    const int* __restrict__ counts, const int* __restrict__ basep,
    const int* __restrict__ rowmap, unsigned short* __restrict__ act)
{
    const int e = blockIdx.z;
    const int nrows = counts[e];
    const int m0 = blockIdx.y * BM;
    if (m0 >= nrows) return;
    const int f0 = blockIdx.x * BN;
    const int gbase = basep[e];

    __shared__ __align__(16) unsigned short At[BM][LDK];
    __shared__ __align__(16) unsigned short B1t[BN][LDK];
    __shared__ __align__(16) unsigned short B3t[BN][LDK];

    const int t = threadIdx.x;
    const int lane = t & 63;
    const int wave = t >> 6;
    const int wr = wave >> 1, wc = wave & 1;

    // A staging: row = t>>1, half = t&1 (each thread 4 x 16B per K-step)
    const int arow = t >> 1;
    const int ahalf = t & 1;
    const int atok = rowmap[gbase + min(m0 + arow, nrows - 1)];
    const unsigned short* aptr = xb + (size_t)atok * HD + ahalf * 32;

    // B staging: thread owns n-quad nq (4 cols) x k-group kg (8 rows)
    const int nq = t >> 3, kg = t & 7;
    const size_t wboff = (size_t)e * HD * FD + (size_t)(kg * 8) * FD + f0 + nq * 4;
    const float* b1p = w1 + wboff;
    const float* b3p = w3 + wboff;

    f32x4 acc1[4][4], acc3[4][4];
#pragma unroll
    for (int i = 0; i < 4; i++)
#pragma unroll
        for (int j = 0; j < 4; j++) { acc1[i][j] = (f32x4)(0.f); acc3[i][j] = (f32x4)(0.f); }

    for (int k0 = 0; k0 < HD; k0 += BK) {
        // ---- global -> regs ----
        uint4 av[4];
#pragma unroll
        for (int i = 0; i < 4; i++) av[i] = *(const uint4*)(aptr + k0 + i * 8);
        float b1v[8][4], b3v[8][4];
#pragma unroll
        for (int kk = 0; kk < 8; kk++) {
            float4 q = *(const float4*)(b1p + (size_t)(k0 + kk) * FD);
            b1v[kk][0] = q.x; b1v[kk][1] = q.y; b1v[kk][2] = q.z; b1v[kk][3] = q.w;
            float4 r = *(const float4*)(b3p + (size_t)(k0 + kk) * FD);
            b3v[kk][0] = r.x; b3v[kk][1] = r.y; b3v[kk][2] = r.z; b3v[kk][3] = r.w;
        }
        __syncthreads();
        // ---- regs -> LDS (A linear; B transposed to [n][k] with fp32->bf16) ----
#pragma unroll
        for (int i = 0; i < 4; i++)
            *(uint4*)&At[arow][ahalf * 32 + i * 8] = av[i];
#pragma unroll
        for (int j = 0; j < 4; j++) {
            unsigned short p1[8], p3[8];
#pragma unroll
            for (int kk = 0; kk < 8; kk++) { p1[kk] = f2bf(b1v[kk][j]); p3[kk] = f2bf(b3v[kk][j]); }
            *(uint4*)&B1t[nq * 4 + j][kg * 8] = *(uint4*)p1;
            *(uint4*)&B3t[nq * 4 + j][kg * 8] = *(uint4*)p3;
        }
        __syncthreads();
        // ---- MFMA ----
#pragma unroll
        for (int kk = 0; kk < 2; kk++) {
            const int kb = kk * 32 + ((lane >> 4) << 3);
            short8 af[4], b1f[4], b3f[4];
#pragma unroll
            for (int i = 0; i < 4; i++)
                af[i] = *(const short8*)&At[wr * 64 + i * 16 + (lane & 15)][kb];
#pragma unroll
            for (int j = 0; j < 4; j++) {
                b1f[j] = *(const short8*)&B1t[wc * 64 + j * 16 + (lane & 15)][kb];
                b3f[j] = *(const short8*)&B3t[wc * 64 + j * 16 + (lane & 15)][kb];
            }
#pragma unroll
            for (int i = 0; i < 4; i++)
#pragma unroll
                for (int j = 0; j < 4; j++) {
                    acc1[i][j] = __builtin_amdgcn_mfma_f32_16x16x32_bf16(af[i], b1f[j], acc1[i][j], 0, 0, 0);
                    acc3[i][j] = __builtin_amdgcn_mfma_f32_16x16x32_bf16(af[i], b3f[j], acc3[i][j], 0, 0, 0);
                }
        }
    }
    // ---- epilogue: SwiGLU, store bf16 act ----
    const int rbase = wr * 64 + ((lane >> 4) << 2);
    const int cbase = f0 + wc * 64 + (lane & 15);
#pragma unroll
    for (int i = 0; i < 4; i++) {
#pragma unroll
        for (int r = 0; r < 4; r++) {
            const int ml = rbase + i * 16 + r;
            if (m0 + ml < nrows) {
                const size_t rowoff = (size_t)(gbase + m0 + ml) * FD;
#pragma unroll
                for (int j = 0; j < 4; j++) {
                    float y1 = acc1[i][j][r];
                    float y3 = acc3[i][j][r];
                    float sv = (y1 / (1.f + __expf(-y1))) * y3;
                    act[rowoff + cbase + j * 16] = f2bf(sv);
                }
            }
        }
    }
}

// ---------------- GEMM2: partial[slot][token] = weight * (act @ W2) ----------------
__global__ __launch_bounds__(256, 2) void k_gemm2(
    const unsigned short* __restrict__ act,
    const float* __restrict__ w2,
    const int* __restrict__ counts, const int* __restrict__ basep,
    const int* __restrict__ rowmap, const int* __restrict__ rowk,
    const float* __restrict__ roww, float* __restrict__ partial)
{
    const int e = blockIdx.z;
    const int nrows = counts[e];
    const int m0 = blockIdx.y * BM;
    if (m0 >= nrows) return;
    const int h0 = blockIdx.x * BN;
    const int gbase = basep[e];

    __shared__ __align__(16) unsigned short At[BM][LDK];
    __shared__ __align__(16) unsigned short Bt[BN][LDK];

    const int t = threadIdx.x;
    const int lane = t & 63;
    const int wave = t >> 6;
    const int wr = wave >> 1, wc = wave & 1;

    const int arow = t >> 1;
    const int ahalf = t & 1;
    const size_t arowidx = (size_t)gbase + min(m0 + arow, nrows - 1);
    const unsigned short* aptr = act + arowidx * FD + ahalf * 32;

    const int nq = t >> 3, kg = t & 7;
    const float* bp = w2 + (size_t)e * FD * HD + (size_t)(kg * 8) * HD + h0 + nq * 4;

    f32x4 acc[4][4];
#pragma unroll
    for (int i = 0; i < 4; i++)
#pragma unroll
        for (int j = 0; j < 4; j++) acc[i][j] = (f32x4)(0.f);

    for (int k0 = 0; k0 < FD; k0 += BK) {
        uint4 av[4];
#pragma unroll
        for (int i = 0; i < 4; i++) av[i] = *(const uint4*)(aptr + k0 + i * 8);
        float bv[8][4];
#pragma unroll
        for (int kk = 0; kk < 8; kk++) {
            float4 q = *(const float4*)(bp + (size_t)(k0 + kk) * HD);
            bv[kk][0] = q.x; bv[kk][1] = q.y; bv[kk][2] = q.z; bv[kk][3] = q.w;
        }
        __syncthreads();
#pragma unroll
        for (int i = 0; i < 4; i++)
            *(uint4*)&At[arow][ahalf * 32 + i * 8] = av[i];
#pragma unroll
        for (int j = 0; j < 4; j++) {
            unsigned short p[8];
#pragma unroll
            for (int kk = 0; kk < 8; kk++) p[kk] = f2bf(bv[kk][j]);
            *(uint4*)&Bt[nq * 4 + j][kg * 8] = *(uint4*)p;
        }
        __syncthreads();
#pragma unroll
        for (int kk = 0; kk < 2; kk++) {
            const int kb = kk * 32 + ((lane >> 4) << 3);
            short8 af[4], bf[4];
#pragma unroll
            for (int i = 0; i < 4; i++)
                af[i] = *(const short8*)&At[wr * 64 + i * 16 + (lane & 15)][kb];
#pragma unroll
            for (int j = 0; j < 4; j++)
                bf[j] = *(const short8*)&Bt[wc * 64 + j * 16 + (lane & 15)][kb];
#pragma unroll
            for (int i = 0; i < 4; i++)
#pragma unroll
                for (int j = 0; j < 4; j++)
                    acc[i][j] = __builtin_amdgcn_mfma_f32_16x16x32_bf16(af[i], bf[j], acc[i][j], 0, 0, 0);
        }
    }
    const int rbase = wr * 64 + ((lane >> 4) << 2);
    const int cbase = h0 + wc * 64 + (lane & 15);
#pragma unroll
    for (int i = 0; i < 4; i++) {
#pragma unroll
        for (int r = 0; r < 4; r++) {
            const int ml = rbase + i * 16 + r;
            if (m0 + ml < nrows) {
                const int grow = gbase + m0 + ml;
                const int tok = rowmap[grow];
                const int slot = rowk[grow];
                const float wv = roww[grow];
                float* op = partial + ((size_t)slot * NTOK + tok) * HD + cbase;
#pragma unroll
                for (int j = 0; j < 4; j++) op[j * 16] = acc[i][j][r] * wv;
            }
        }
    }
}

__global__ void k_combine(const float* __restrict__ partial, float* __restrict__ out) {
    size_t i = ((size_t)blockIdx.x * blockDim.x + threadIdx.x) * 4;
    float4 a = *(const float4*)(partial + i);
    float4 b = *(const float4*)(partial + (size_t)NTOK * HD + i);
    float4 o; o.x = a.x + b.x; o.y = a.y + b.y; o.z = a.z + b.z; o.w = a.w + b.w;
    *(float4*)(out + i) = o;
}

extern "C" void kernel_launch(void* const* d_in, const int* in_sizes, int n_in,
                              void* d_out, int out_size, void* d_ws, size_t ws_size,
                              hipStream_t stream) {
    const float* x  = (const float*)d_in[0];
    const float* gw = (const float*)d_in[1];
    const float* w1 = (const float*)d_in[2];
    const float* w3 = (const float*)d_in[3];
    const float* w2 = (const float*)d_in[4];
    float* out = (float*)d_out;

    char* ws = (char*)d_ws;
    size_t off = 0;
    auto alloc = [&](size_t b) { char* p = ws + off; off += (b + 255) & ~(size_t)255; return p; };
    int*   sel    = (int*)  alloc((size_t)NTOK * 2 * 4);
    float* selw   = (float*)alloc((size_t)NTOK * 2 * 4);
    int*   counts = (int*)  alloc(NE * 4);
    int*   basep  = (int*)  alloc(NE * 4);
    int*   fillc  = (int*)  alloc(NE * 4);
    int*   rowmap = (int*)  alloc((size_t)NTOK * 2 * 4);
    int*   rowk   = (int*)  alloc((size_t)NTOK * 2 * 4);
    float* roww   = (float*)alloc((size_t)NTOK * 2 * 4);
    unsigned short* xb  = (unsigned short*)alloc((size_t)NTOK * HD * 2);
    unsigned short* act = (unsigned short*)alloc((size_t)NTOK * 2 * FD * 2);
    float* partial = (float*)alloc((size_t)2 * NTOK * HD * 4);

    hipMemsetAsync(counts, 0, NE * 4, stream);
    k_cvt<<<(NTOK * HD) / (256 * 8), 256, 0, stream>>>(x, xb);
    k_router<<<NTOK / 4, 256, 0, stream>>>(x, gw, sel, selw, counts);
    k_scan<<<1, 64, 0, stream>>>(counts, basep, fillc);
    k_fill<<<NTOK / 256, 256, 0, stream>>>(sel, selw, basep, fillc, rowmap, rowk, roww);
    k_gemm1<<<dim3(FD / BN, NTOK / BM, NE), 256, 0, stream>>>(xb, w1, w3, counts, basep, rowmap, act);
    k_gemm2<<<dim3(HD / BN, NTOK / BM, NE), 256, 0, stream>>>(act, w2, counts, basep, rowmap, rowk, roww, partial);
    k_combine<<<(NTOK * HD) / (256 * 4), 256, 0, stream>>>(partial, out);
}

// Round 2
// 590.702 us; speedup vs baseline: 1.3003x; 1.3003x over previous
//
#include <hip/hip_runtime.h>
#include <hip/hip_bf16.h>

#define NTOK 2048   // B*S
#define HD   1024
#define FD   3584
#define NE   8

#define BM 128
#define BN 128
#define BN2 64      // gemm2 N-tile
#define BK 64
#define LDK 72      // 64 + 8 bf16 pad -> 144B row stride, spreads banks on b128 reads

typedef __attribute__((ext_vector_type(8))) short short8;
typedef __attribute__((ext_vector_type(4))) float f32x4;

__device__ __forceinline__ unsigned short f2bf(float f) {
    __hip_bfloat16 h = __float2bfloat16(f);
    union { __hip_bfloat16 h; unsigned short u; } c; c.h = h;
    return c.u;
}

// ---------------- router: fp32 logits, softmax, top-2, renorm ----------------
__global__ void k_router(const float* __restrict__ x, const float* __restrict__ gw,
                         int* __restrict__ sel, float* __restrict__ selw,
                         int* __restrict__ counts) {
    int token = blockIdx.x * 4 + (threadIdx.x >> 6);
    int lane  = threadIdx.x & 63;
    if (token >= NTOK) return;
    const float* xr = x + (size_t)token * HD;
    float acc[NE];
#pragma unroll
    for (int e = 0; e < NE; e++) acc[e] = 0.f;
    for (int h = lane; h < HD; h += 64) {
        float xv = xr[h];
        const float4* g = (const float4*)(gw + (size_t)h * NE);
        float4 g0 = g[0], g1 = g[1];
        acc[0] += xv * g0.x; acc[1] += xv * g0.y; acc[2] += xv * g0.z; acc[3] += xv * g0.w;
        acc[4] += xv * g1.x; acc[5] += xv * g1.y; acc[6] += xv * g1.z; acc[7] += xv * g1.w;
    }
#pragma unroll
    for (int e = 0; e < NE; e++) {
#pragma unroll
        for (int off = 32; off >= 1; off >>= 1) acc[e] += __shfl_xor(acc[e], off, 64);
    }
    if (lane == 0) {
        float m = acc[0];
#pragma unroll
        for (int e = 1; e < NE; e++) m = fmaxf(m, acc[e]);
        float z[NE];
#pragma unroll
        for (int e = 0; e < NE; e++) z[e] = expf(acc[e] - m);
        int e0 = 0; float z0 = z[0];
#pragma unroll
        for (int e = 1; e < NE; e++) if (z[e] > z0) { z0 = z[e]; e0 = e; }
        int e1 = -1; float z1 = -1.f;
#pragma unroll
        for (int e = 0; e < NE; e++) if (e != e0 && z[e] > z1) { z1 = z[e]; e1 = e; }
        float s = z0 + z1;
        sel[token * 2 + 0] = e0; sel[token * 2 + 1] = e1;
        selw[token * 2 + 0] = z0 / s; selw[token * 2 + 1] = z1 / s;
        atomicAdd(&counts[e0], 1);
        atomicAdd(&counts[e1], 1);
    }
}

__global__ void k_scan(const int* __restrict__ counts, int* __restrict__ basep,
                       int* __restrict__ fillc) {
    if (threadIdx.x == 0 && blockIdx.x == 0) {
        int b = 0;
        for (int e = 0; e < NE; e++) { basep[e] = b; b += counts[e]; fillc[e] = 0; }
    }
}

__global__ void k_fill(const int* __restrict__ sel, const float* __restrict__ selw,
                       const int* __restrict__ basep, int* __restrict__ fillc,
                       int* __restrict__ rowmap, int* __restrict__ rowk,
                       float* __restrict__ roww) {
    int n = blockIdx.x * blockDim.x + threadIdx.x;
    if (n >= NTOK) return;
#pragma unroll
    for (int k = 0; k < 2; k++) {
        int e = sel[n * 2 + k];
        int p = atomicAdd(&fillc[e], 1);
        int g = basep[e] + p;
        rowmap[g] = n; rowk[g] = k; roww[g] = selw[n * 2 + k];
    }
}

// ---------------- x -> bf16 ----------------
__global__ void k_cvt(const float* __restrict__ x, unsigned short* __restrict__ xb) {
    size_t i = ((size_t)blockIdx.x * blockDim.x + threadIdx.x) * 8;
    float4 a = *(const float4*)(x + i);
    float4 b = *(const float4*)(x + i + 4);
    unsigned short p[8] __attribute__((aligned(16))) =
        { f2bf(a.x), f2bf(a.y), f2bf(a.z), f2bf(a.w),
          f2bf(b.x), f2bf(b.y), f2bf(b.z), f2bf(b.w) };
    *(uint4*)(xb + i) = *(uint4*)p;
}

// ---------------- GEMM1: act = silu(X@W1) * (X@W3), grouped by expert ----------------
__global__ __launch_bounds__(256, 2) void k_gemm1(
    const unsigned short* __restrict__ xb,
    const float* __restrict__ w1, const float* __restrict__ w3,
    const int* __restrict__ counts, const int* __restrict__ basep,
    const int* __restrict__ rowmap, unsigned short* __restrict__ act)
{
    const int e = blockIdx.z;
    const int nrows = counts[e];
    const int m0 = blockIdx.y * BM;
    if (m0 >= nrows) return;
    const int f0 = blockIdx.x * BN;
    const int gbase = basep[e];

    __shared__ __align__(16) unsigned short At[BM][LDK];
    __shared__ __align__(16) unsigned short B1t[BN][LDK];
    __shared__ __align__(16) unsigned short B3t[BN][LDK];

    const int t = threadIdx.x;
    const int lane = t & 63;
    const int wave = t >> 6;
    const int wr = wave >> 1, wc = wave & 1;

    const int arow = t >> 1;
    const int ahalf = t & 1;
    const int atok = rowmap[gbase + min(m0 + arow, nrows - 1)];
    const unsigned short* aptr = xb + (size_t)atok * HD + ahalf * 32;

    const int nq = t >> 3, kg = t & 7;
    const size_t wboff = (size_t)e * HD * FD + (size_t)(kg * 8) * FD + f0 + nq * 4;
    const float* b1p = w1 + wboff;
    const float* b3p = w3 + wboff;

    f32x4 acc1[4][4], acc3[4][4];
#pragma unroll
    for (int i = 0; i < 4; i++)
#pragma unroll
        for (int j = 0; j < 4; j++) { acc1[i][j] = (f32x4)(0.f); acc3[i][j] = (f32x4)(0.f); }

    uint4 av[4];
    float4 b1q[8], b3q[8];
    // prologue: load k-tile 0
#pragma unroll
    for (int i = 0; i < 4; i++) av[i] = *(const uint4*)(aptr + i * 8);
#pragma unroll
    for (int kk = 0; kk < 8; kk++) {
        b1q[kk] = *(const float4*)(b1p + (size_t)kk * FD);
        b3q[kk] = *(const float4*)(b3p + (size_t)kk * FD);
    }

    for (int k0 = 0; k0 < HD; k0 += BK) {
        __syncthreads();   // all waves done reading previous LDS tile
        // ---- regs -> LDS (A linear; B transposed to [n][k] with fp32->bf16) ----
#pragma unroll
        for (int i = 0; i < 4; i++)
            *(uint4*)&At[arow][ahalf * 32 + i * 8] = av[i];
#pragma unroll
        for (int j = 0; j < 4; j++) {
            unsigned short p1[8] __attribute__((aligned(16)));
            unsigned short p3[8] __attribute__((aligned(16)));
#pragma unroll
            for (int kk = 0; kk < 8; kk++) {
                p1[kk] = f2bf(((const float*)&b1q[kk])[j]);
                p3[kk] = f2bf(((const float*)&b3q[kk])[j]);
            }
            *(uint4*)&B1t[nq * 4 + j][kg * 8] = *(uint4*)p1;
            *(uint4*)&B3t[nq * 4 + j][kg * 8] = *(uint4*)p3;
        }
        __syncthreads();
        // ---- prefetch next k-tile (overlaps MFMA below) ----
        if (k0 + BK < HD) {
            const int kn = k0 + BK;
#pragma unroll
            for (int i = 0; i < 4; i++) av[i] = *(const uint4*)(aptr + kn + i * 8);
#pragma unroll
            for (int kk = 0; kk < 8; kk++) {
                b1q[kk] = *(const float4*)(b1p + (size_t)(kn + kk) * FD);
                b3q[kk] = *(const float4*)(b3p + (size_t)(kn + kk) * FD);
            }
        }
        // ---- MFMA ----
#pragma unroll
        for (int kk = 0; kk < 2; kk++) {
            const int kb = kk * 32 + ((lane >> 4) << 3);
            short8 af[4], b1f[4], b3f[4];
#pragma unroll
            for (int i = 0; i < 4; i++)
                af[i] = *(const short8*)&At[wr * 64 + i * 16 + (lane & 15)][kb];
#pragma unroll
            for (int j = 0; j < 4; j++) {
                b1f[j] = *(const short8*)&B1t[wc * 64 + j * 16 + (lane & 15)][kb];
                b3f[j] = *(const short8*)&B3t[wc * 64 + j * 16 + (lane & 15)][kb];
            }
#pragma unroll
            for (int i = 0; i < 4; i++)
#pragma unroll
                for (int j = 0; j < 4; j++) {
                    acc1[i][j] = __builtin_amdgcn_mfma_f32_16x16x32_bf16(af[i], b1f[j], acc1[i][j], 0, 0, 0);
                    acc3[i][j] = __builtin_amdgcn_mfma_f32_16x16x32_bf16(af[i], b3f[j], acc3[i][j], 0, 0, 0);
                }
        }
    }
    // ---- epilogue: SwiGLU, store bf16 act ----
    const int rbase = wr * 64 + ((lane >> 4) << 2);
    const int cbase = f0 + wc * 64 + (lane & 15);
#pragma unroll
    for (int i = 0; i < 4; i++) {
#pragma unroll
        for (int r = 0; r < 4; r++) {
            const int ml = rbase + i * 16 + r;
            if (m0 + ml < nrows) {
                const size_t rowoff = (size_t)(gbase + m0 + ml) * FD;
#pragma unroll
                for (int j = 0; j < 4; j++) {
                    float y1 = acc1[i][j][r];
                    float y3 = acc3[i][j][r];
                    float sv = (y1 / (1.f + __expf(-y1))) * y3;
                    act[rowoff + cbase + j * 16] = f2bf(sv);
                }
            }
        }
    }
}

// ---------------- GEMM2: partial[slot][token] = weight * (act @ W2) ----------------
// BM=128 x BN2=64 tile, 4 waves each 64x32. Pipelined like gemm1.
__global__ __launch_bounds__(256, 2) void k_gemm2(
    const unsigned short* __restrict__ act,
    const float* __restrict__ w2,
    const int* __restrict__ counts, const int* __restrict__ basep,
    const int* __restrict__ rowmap, const int* __restrict__ rowk,
    const float* __restrict__ roww, float* __restrict__ partial)
{
    const int e = blockIdx.z;
    const int nrows = counts[e];
    const int m0 = blockIdx.y * BM;
    if (m0 >= nrows) return;
    const int h0 = blockIdx.x * BN2;
    const int gbase = basep[e];

    __shared__ __align__(16) unsigned short At[BM][LDK];
    __shared__ __align__(16) unsigned short Bt[BN2][LDK];

    const int t = threadIdx.x;
    const int lane = t & 63;
    const int wave = t >> 6;
    const int wr = wave >> 1, wc = wave & 1;

    const int arow = t >> 1;
    const int ahalf = t & 1;
    const size_t arowidx = (size_t)gbase + min(m0 + arow, nrows - 1);
    const unsigned short* aptr = act + arowidx * FD + ahalf * 32;

    // B staging: kq = t>>4 (0..15) owns 4 k-rows; nq = t&15 (0..15) owns 4 cols.
    // For fixed kk a wave reads 4 rows x 256B contiguous -> good coalescing.
    const int kq = t >> 4, nq = t & 15;
    const float* bp = w2 + (size_t)e * FD * HD + (size_t)(kq * 4) * HD + h0 + nq * 4;

    f32x4 acc[4][2];
#pragma unroll
    for (int i = 0; i < 4; i++)
#pragma unroll
        for (int j = 0; j < 2; j++) acc[i][j] = (f32x4)(0.f);

    uint4 av[4];
    float4 bq[4];
#pragma unroll
    for (int i = 0; i < 4; i++) av[i] = *(const uint4*)(aptr + i * 8);
#pragma unroll
    for (int kk = 0; kk < 4; kk++) bq[kk] = *(const float4*)(bp + (size_t)kk * HD);

    for (int k0 = 0; k0 < FD; k0 += BK) {
        __syncthreads();
#pragma unroll
        for (int i = 0; i < 4; i++)
            *(uint4*)&At[arow][ahalf * 32 + i * 8] = av[i];
#pragma unroll
        for (int c = 0; c < 4; c++) {
            unsigned int lo = (unsigned int)f2bf(((const float*)&bq[0])[c])
                            | ((unsigned int)f2bf(((const float*)&bq[1])[c]) << 16);
            unsigned int hi = (unsigned int)f2bf(((const float*)&bq[2])[c])
                            | ((unsigned int)f2bf(((const float*)&bq[3])[c]) << 16);
            uint2 v; v.x = lo; v.y = hi;
            *(uint2*)&Bt[nq * 4 + c][kq * 4] = v;
        }
        __syncthreads();
        if (k0 + BK < FD) {
            const int kn = k0 + BK;
#pragma unroll
            for (int i = 0; i < 4; i++) av[i] = *(const uint4*)(aptr + kn + i * 8);
#pragma unroll
            for (int kk = 0; kk < 4; kk++) bq[kk] = *(const float4*)(bp + (size_t)(kn + kk) * HD);
        }
#pragma unroll
        for (int kk = 0; kk < 2; kk++) {
            const int kb = kk * 32 + ((lane >> 4) << 3);
            short8 af[4], bf[2];
#pragma unroll
            for (int i = 0; i < 4; i++)
                af[i] = *(const short8*)&At[wr * 64 + i * 16 + (lane & 15)][kb];
#pragma unroll
            for (int j = 0; j < 2; j++)
                bf[j] = *(const short8*)&Bt[wc * 32 + j * 16 + (lane & 15)][kb];
#pragma unroll
            for (int i = 0; i < 4; i++)
#pragma unroll
                for (int j = 0; j < 2; j++)
                    acc[i][j] = __builtin_amdgcn_mfma_f32_16x16x32_bf16(af[i], bf[j], acc[i][j], 0, 0, 0);
        }
    }
    const int rbase = wr * 64 + ((lane >> 4) << 2);
    const int cbase = h0 + wc * 32 + (lane & 15);
#pragma unroll
    for (int i = 0; i < 4; i++) {
#pragma unroll
        for (int r = 0; r < 4; r++) {
            const int ml = rbase + i * 16 + r;
            if (m0 + ml < nrows) {
                const int grow = gbase + m0 + ml;
                const int tok = rowmap[grow];
                const int slot = rowk[grow];
                const float wv = roww[grow];
                float* op = partial + ((size_t)slot * NTOK + tok) * HD + cbase;
#pragma unroll
                for (int j = 0; j < 2; j++) op[j * 16] = acc[i][j][r] * wv;
            }
        }
    }
}

__global__ void k_combine(const float* __restrict__ partial, float* __restrict__ out) {
    size_t i = ((size_t)blockIdx.x * blockDim.x + threadIdx.x) * 4;
    float4 a = *(const float4*)(partial + i);
    float4 b = *(const float4*)(partial + (size_t)NTOK * HD + i);
    float4 o; o.x = a.x + b.x; o.y = a.y + b.y; o.z = a.z + b.z; o.w = a.w + b.w;
    *(float4*)(out + i) = o;
}

extern "C" void kernel_launch(void* const* d_in, const int* in_sizes, int n_in,
                              void* d_out, int out_size, void* d_ws, size_t ws_size,
                              hipStream_t stream) {
    const float* x  = (const float*)d_in[0];
    const float* gw = (const float*)d_in[1];
    const float* w1 = (const float*)d_in[2];
    const float* w3 = (const float*)d_in[3];
    const float* w2 = (const float*)d_in[4];
    float* out = (float*)d_out;

    char* ws = (char*)d_ws;
    size_t off = 0;
    auto alloc = [&](size_t b) { char* p = ws + off; off += (b + 255) & ~(size_t)255; return p; };
    int*   sel    = (int*)  alloc((size_t)NTOK * 2 * 4);
    float* selw   = (float*)alloc((size_t)NTOK * 2 * 4);
    int*   counts = (int*)  alloc(NE * 4);
    int*   basep  = (int*)  alloc(NE * 4);
    int*   fillc  = (int*)  alloc(NE * 4);
    int*   rowmap = (int*)  alloc((size_t)NTOK * 2 * 4);
    int*   rowk   = (int*)  alloc((size_t)NTOK * 2 * 4);
    float* roww   = (float*)alloc((size_t)NTOK * 2 * 4);
    unsigned short* xb  = (unsigned short*)alloc((size_t)NTOK * HD * 2);
    unsigned short* act = (unsigned short*)alloc((size_t)NTOK * 2 * FD * 2);
    float* partial = (float*)alloc((size_t)2 * NTOK * HD * 4);

    hipMemsetAsync(counts, 0, NE * 4, stream);
    k_cvt<<<(NTOK * HD) / (256 * 8), 256, 0, stream>>>(x, xb);
    k_router<<<NTOK / 4, 256, 0, stream>>>(x, gw, sel, selw, counts);
    k_scan<<<1, 64, 0, stream>>>(counts, basep, fillc);
    k_fill<<<NTOK / 256, 256, 0, stream>>>(sel, selw, basep, fillc, rowmap, rowk, roww);
    k_gemm1<<<dim3(FD / BN, NTOK / BM, NE), 256, 0, stream>>>(xb, w1, w3, counts, basep, rowmap, act);
    k_gemm2<<<dim3(HD / BN2, NTOK / BM, NE), 256, 0, stream>>>(act, w2, counts, basep, rowmap, rowk, roww, partial);
    k_combine<<<(NTOK * HD) / (256 * 4), 256, 0, stream>>>(partial, out);
}

// Round 3
// 391.988 us; speedup vs baseline: 1.9595x; 1.5069x over previous
//
#include <hip/hip_runtime.h>
#include <hip/hip_bf16.h>

#define NTOK 2048   // B*S
#define HD   1024
#define FD   3584
#define NE   8

#define BM 128
#define BN 128      // gemm1 f-tile
#define BN2 64      // gemm2 h-tile
#define BK 64

typedef __attribute__((ext_vector_type(8))) short short8;
typedef __attribute__((ext_vector_type(4))) float f32x4;

__device__ __forceinline__ unsigned short f2bf(float f) {
    __hip_bfloat16 h = __float2bfloat16(f);
    union { __hip_bfloat16 h; unsigned short u; } c; c.h = h;
    return c.u;
}

// global_load_lds width=16: per-lane 16B global src -> wave-uniform LDS base + lane*16
typedef __attribute__((address_space(1))) const unsigned int g_cu32;
typedef __attribute__((address_space(3))) unsigned int l_u32;
__device__ __forceinline__ void gl16(const void* g, void* l) {
    __builtin_amdgcn_global_load_lds((g_cu32*)g, (l_u32*)(unsigned int)(size_t)l, 16, 0, 0);
}

// ---------------- router: fp32 logits, softmax, top-2, renorm ----------------
__global__ void k_router(const float* __restrict__ x, const float* __restrict__ gw,
                         int* __restrict__ sel, float* __restrict__ selw,
                         int* __restrict__ counts) {
    int token = blockIdx.x * 4 + (threadIdx.x >> 6);
    int lane  = threadIdx.x & 63;
    if (token >= NTOK) return;
    const float* xr = x + (size_t)token * HD;
    float acc[NE];
#pragma unroll
    for (int e = 0; e < NE; e++) acc[e] = 0.f;
    for (int h = lane; h < HD; h += 64) {
        float xv = xr[h];
        const float4* g = (const float4*)(gw + (size_t)h * NE);
        float4 g0 = g[0], g1 = g[1];
        acc[0] += xv * g0.x; acc[1] += xv * g0.y; acc[2] += xv * g0.z; acc[3] += xv * g0.w;
        acc[4] += xv * g1.x; acc[5] += xv * g1.y; acc[6] += xv * g1.z; acc[7] += xv * g1.w;
    }
#pragma unroll
    for (int e = 0; e < NE; e++) {
#pragma unroll
        for (int off = 32; off >= 1; off >>= 1) acc[e] += __shfl_xor(acc[e], off, 64);
    }
    if (lane == 0) {
        float m = acc[0];
#pragma unroll
        for (int e = 1; e < NE; e++) m = fmaxf(m, acc[e]);
        float z[NE];
#pragma unroll
        for (int e = 0; e < NE; e++) z[e] = expf(acc[e] - m);
        int e0 = 0; float z0 = z[0];
#pragma unroll
        for (int e = 1; e < NE; e++) if (z[e] > z0) { z0 = z[e]; e0 = e; }
        int e1 = -1; float z1 = -1.f;
#pragma unroll
        for (int e = 0; e < NE; e++) if (e != e0 && z[e] > z1) { z1 = z[e]; e1 = e; }
        float s = z0 + z1;
        sel[token * 2 + 0] = e0; sel[token * 2 + 1] = e1;
        selw[token * 2 + 0] = z0 / s; selw[token * 2 + 1] = z1 / s;
        atomicAdd(&counts[e0], 1);
        atomicAdd(&counts[e1], 1);
    }
}

__global__ void k_scan(const int* __restrict__ counts, int* __restrict__ basep,
                       int* __restrict__ fillc) {
    if (threadIdx.x == 0 && blockIdx.x == 0) {
        int b = 0;
        for (int e = 0; e < NE; e++) { basep[e] = b; b += counts[e]; fillc[e] = 0; }
    }
}

__global__ void k_fill(const int* __restrict__ sel, const float* __restrict__ selw,
                       const int* __restrict__ basep, int* __restrict__ fillc,
                       int* __restrict__ rowmap, int* __restrict__ rowk,
                       float* __restrict__ roww) {
    int n = blockIdx.x * blockDim.x + threadIdx.x;
    if (n >= NTOK) return;
#pragma unroll
    for (int k = 0; k < 2; k++) {
        int e = sel[n * 2 + k];
        int p = atomicAdd(&fillc[e], 1);
        int g = basep[e] + p;
        rowmap[g] = n; rowk[g] = k; roww[g] = selw[n * 2 + k];
    }
}

// ---------------- x -> bf16 ----------------
__global__ void k_cvt(const float* __restrict__ x, unsigned short* __restrict__ xb) {
    size_t i = ((size_t)blockIdx.x * blockDim.x + threadIdx.x) * 8;
    float4 a = *(const float4*)(x + i);
    float4 b = *(const float4*)(x + i + 4);
    unsigned short p[8] __attribute__((aligned(16))) =
        { f2bf(a.x), f2bf(a.y), f2bf(a.z), f2bf(a.w),
          f2bf(b.x), f2bf(b.y), f2bf(b.z), f2bf(b.w) };
    *(uint4*)(xb + i) = *(uint4*)p;
}

// ---------------- weight transpose+convert: [E][K][N] f32 -> [E][N][K] bf16 ----------------
__global__ void k_wt(const float* __restrict__ w, unsigned short* __restrict__ wt,
                     int K, int N) {
    __shared__ unsigned short tile[64][66];
    const int t = threadIdx.x;
    const float* src = w + (size_t)blockIdx.z * K * N + ((size_t)blockIdx.y * 64) * N + blockIdx.x * 64;
    {
        const int r = t >> 4;
        const int c4 = (t & 15) * 4;
#pragma unroll
        for (int i = 0; i < 4; i++) {
            const int kr = r + i * 16;
            float4 v = *(const float4*)(src + (size_t)kr * N + c4);
            unsigned short p[4] = { f2bf(v.x), f2bf(v.y), f2bf(v.z), f2bf(v.w) };
            *(unsigned int*)&tile[kr][c4]     = *(unsigned int*)&p[0];
            *(unsigned int*)&tile[kr][c4 + 2] = *(unsigned int*)&p[2];
        }
    }
    __syncthreads();
    unsigned short* dst = wt + (size_t)blockIdx.z * N * K + ((size_t)blockIdx.x * 64) * K + blockIdx.y * 64;
    const int n = t >> 3;
    const int kc = (t & 7) * 8;
#pragma unroll
    for (int i = 0; i < 2; i++) {
        const int nn = n + i * 32;
        unsigned short p[8] __attribute__((aligned(16)));
#pragma unroll
        for (int j = 0; j < 8; j++) p[j] = tile[kc + j][nn];
        *(uint4*)&dst[(size_t)nn * K + kc] = *(uint4*)p;
    }
}

// ---------------- GEMM1: act = silu(X@W1) * (X@W3), m97-style gload_lds ----------------
__global__ __launch_bounds__(256, 2) void k_gemm1(
    const unsigned short* __restrict__ xb,
    const unsigned short* __restrict__ w1t, const unsigned short* __restrict__ w3t,
    const int* __restrict__ counts, const int* __restrict__ basep,
    const int* __restrict__ rowmap, unsigned short* __restrict__ act)
{
    const int e = blockIdx.z;
    const int nrows = counts[e];
    const int m0 = blockIdx.y * BM;
    if (m0 >= nrows) return;
    const int f0 = blockIdx.x * BN;
    const int gbase = basep[e];

    __shared__ __align__(16) unsigned short At[BM][BK];
    __shared__ __align__(16) unsigned short B1[BN][BK];
    __shared__ __align__(16) unsigned short B3[BN][BK];

    const int t = threadIdx.x;
    const int lane = t & 63;
    const int w = t >> 6;
    const int wr = w >> 1, wc = w & 1;
    const int lr = lane >> 3;                 // row within 8-row chunk
    const int so = ((lane & 7) ^ lr) * 8;     // pre-swizzled in-row element offset

    const unsigned short* asrc[4];
    const unsigned short* b1src[4];
    const unsigned short* b3src[4];
#pragma unroll
    for (int c = 0; c < 4; c++) {
        const int row = (w * 4 + c) * 8 + lr;
        const int tok = rowmap[gbase + min(m0 + row, nrows - 1)];
        asrc[c]  = xb  + (size_t)tok * HD + so;
        b1src[c] = w1t + ((size_t)(e * FD + f0 + row)) * HD + so;
        b3src[c] = w3t + ((size_t)(e * FD + f0 + row)) * HD + so;
    }

    f32x4 acc1[4][4], acc3[4][4];
#pragma unroll
    for (int i = 0; i < 4; i++)
#pragma unroll
        for (int j = 0; j < 4; j++) { acc1[i][j] = (f32x4)(0.f); acc3[i][j] = (f32x4)(0.f); }

    const int l15 = lane & 15;
    const int lhi = lane >> 4;
    const int rs = (l15 & 7) * 8;             // read-side swizzle (row&7)*8

    for (int k0 = 0; k0 < HD; k0 += BK) {
#pragma unroll
        for (int c = 0; c < 4; c++) {
            gl16(asrc[c]  + k0, &At[(w * 4 + c) * 8][0]);
            gl16(b1src[c] + k0, &B1[(w * 4 + c) * 8][0]);
            gl16(b3src[c] + k0, &B3[(w * 4 + c) * 8][0]);
        }
        __syncthreads();
#pragma unroll
        for (int kk = 0; kk < 2; kk++) {
            const int kc = (kk * 32 + lhi * 8) ^ rs;
            short8 af[4], b1f[4], b3f[4];
#pragma unroll
            for (int i = 0; i < 4; i++)
                af[i] = *(const short8*)&At[wr * 64 + i * 16 + l15][kc];
#pragma unroll
            for (int j = 0; j < 4; j++) {
                b1f[j] = *(const short8*)&B1[wc * 64 + j * 16 + l15][kc];
                b3f[j] = *(const short8*)&B3[wc * 64 + j * 16 + l15][kc];
            }
#pragma unroll
            for (int i = 0; i < 4; i++)
#pragma unroll
                for (int j = 0; j < 4; j++) {
                    acc1[i][j] = __builtin_amdgcn_mfma_f32_16x16x32_bf16(af[i], b1f[j], acc1[i][j], 0, 0, 0);
                    acc3[i][j] = __builtin_amdgcn_mfma_f32_16x16x32_bf16(af[i], b3f[j], acc3[i][j], 0, 0, 0);
                }
        }
        __syncthreads();
    }
    // epilogue: SwiGLU, bf16 act
    const int rbase = wr * 64 + lhi * 4;
    const int cbase = f0 + wc * 64 + l15;
#pragma unroll
    for (int i = 0; i < 4; i++) {
#pragma unroll
        for (int r = 0; r < 4; r++) {
            const int ml = rbase + i * 16 + r;
            if (m0 + ml < nrows) {
                const size_t rowoff = (size_t)(gbase + m0 + ml) * FD;
#pragma unroll
                for (int j = 0; j < 4; j++) {
                    float y1 = acc1[i][j][r];
                    float y3 = acc3[i][j][r];
                    float sv = (y1 / (1.f + __expf(-y1))) * y3;
                    act[rowoff + cbase + j * 16] = f2bf(sv);
                }
            }
        }
    }
}

// ---------------- GEMM2: partial[slot][token] = weight * (act @ W2), m97-style ----------------
__global__ __launch_bounds__(256, 4) void k_gemm2(
    const unsigned short* __restrict__ act,
    const unsigned short* __restrict__ w2t,
    const int* __restrict__ counts, const int* __restrict__ basep,
    const int* __restrict__ rowmap, const int* __restrict__ rowk,
    const float* __restrict__ roww, float* __restrict__ partial)
{
    const int e = blockIdx.z;
    const int nrows = counts[e];
    const int m0 = blockIdx.y * BM;
    if (m0 >= nrows) return;
    const int h0 = blockIdx.x * BN2;
    const int gbase = basep[e];

    __shared__ __align__(16) unsigned short At[BM][BK];
    __shared__ __align__(16) unsigned short Bt[BN2][BK];

    const int t = threadIdx.x;
    const int lane = t & 63;
    const int w = t >> 6;
    const int wr = w >> 1, wc = w & 1;
    const int lr = lane >> 3;
    const int so = ((lane & 7) ^ lr) * 8;

    const unsigned short* asrc[4];
    const unsigned short* bsrc[2];
#pragma unroll
    for (int c = 0; c < 4; c++) {
        const int row = (w * 4 + c) * 8 + lr;
        const size_t grow = (size_t)gbase + min(m0 + row, nrows - 1);
        asrc[c] = act + grow * FD + so;
    }
#pragma unroll
    for (int c = 0; c < 2; c++) {
        const int row = (w * 2 + c) * 8 + lr;
        bsrc[c] = w2t + ((size_t)(e * HD + h0 + row)) * FD + so;
    }

    f32x4 acc[4][2];
#pragma unroll
    for (int i = 0; i < 4; i++)
#pragma unroll
        for (int j = 0; j < 2; j++) acc[i][j] = (f32x4)(0.f);

    const int l15 = lane & 15;
    const int lhi = lane >> 4;
    const int rs = (l15 & 7) * 8;

    for (int k0 = 0; k0 < FD; k0 += BK) {
#pragma unroll
        for (int c = 0; c < 4; c++)
            gl16(asrc[c] + k0, &At[(w * 4 + c) * 8][0]);
#pragma unroll
        for (int c = 0; c < 2; c++)
            gl16(bsrc[c] + k0, &Bt[(w * 2 + c) * 8][0]);
        __syncthreads();
#pragma unroll
        for (int kk = 0; kk < 2; kk++) {
            const int kc = (kk * 32 + lhi * 8) ^ rs;
            short8 af[4], bf[2];
#pragma unroll
            for (int i = 0; i < 4; i++)
                af[i] = *(const short8*)&At[wr * 64 + i * 16 + l15][kc];
#pragma unroll
            for (int j = 0; j < 2; j++)
                bf[j] = *(const short8*)&Bt[wc * 32 + j * 16 + l15][kc];
#pragma unroll
            for (int i = 0; i < 4; i++)
#pragma unroll
                for (int j = 0; j < 2; j++)
                    acc[i][j] = __builtin_amdgcn_mfma_f32_16x16x32_bf16(af[i], bf[j], acc[i][j], 0, 0, 0);
        }
        __syncthreads();
    }
    const int rbase = wr * 64 + lhi * 4;
    const int cbase = h0 + wc * 32 + l15;
#pragma unroll
    for (int i = 0; i < 4; i++) {
#pragma unroll
        for (int r = 0; r < 4; r++) {
            const int ml = rbase + i * 16 + r;
            if (m0 + ml < nrows) {
                const int grow = gbase + m0 + ml;
                const int tok = rowmap[grow];
                const int slot = rowk[grow];
                const float wv = roww[grow];
                float* op = partial + ((size_t)slot * NTOK + tok) * HD + cbase;
#pragma unroll
                for (int j = 0; j < 2; j++) op[j * 16] = acc[i][j][r] * wv;
            }
        }
    }
}

__global__ void k_combine(const float* __restrict__ partial, float* __restrict__ out) {
    size_t i = ((size_t)blockIdx.x * blockDim.x + threadIdx.x) * 4;
    float4 a = *(const float4*)(partial + i);
    float4 b = *(const float4*)(partial + (size_t)NTOK * HD + i);
    float4 o; o.x = a.x + b.x; o.y = a.y + b.y; o.z = a.z + b.z; o.w = a.w + b.w;
    *(float4*)(out + i) = o;
}

extern "C" void kernel_launch(void* const* d_in, const int* in_sizes, int n_in,
                              void* d_out, int out_size, void* d_ws, size_t ws_size,
                              hipStream_t stream) {
    const float* x  = (const float*)d_in[0];
    const float* gw = (const float*)d_in[1];
    const float* w1 = (const float*)d_in[2];
    const float* w3 = (const float*)d_in[3];
    const float* w2 = (const float*)d_in[4];
    float* out = (float*)d_out;

    char* ws = (char*)d_ws;
    size_t off = 0;
    auto alloc = [&](size_t b) { char* p = ws + off; off += (b + 255) & ~(size_t)255; return p; };
    int*   sel    = (int*)  alloc((size_t)NTOK * 2 * 4);
    float* selw   = (float*)alloc((size_t)NTOK * 2 * 4);
    int*   counts = (int*)  alloc(NE * 4);
    int*   basep  = (int*)  alloc(NE * 4);
    int*   fillc  = (int*)  alloc(NE * 4);
    int*   rowmap = (int*)  alloc((size_t)NTOK * 2 * 4);
    int*   rowk   = (int*)  alloc((size_t)NTOK * 2 * 4);
    float* roww   = (float*)alloc((size_t)NTOK * 2 * 4);
    unsigned short* xb  = (unsigned short*)alloc((size_t)NTOK * HD * 2);
    unsigned short* act = (unsigned short*)alloc((size_t)NTOK * 2 * FD * 2);
    float* partial = (float*)alloc((size_t)2 * NTOK * HD * 4);
    unsigned short* w1t = (unsigned short*)alloc((size_t)NE * HD * FD * 2);
    unsigned short* w3t = (unsigned short*)alloc((size_t)NE * HD * FD * 2);
    unsigned short* w2t = (unsigned short*)alloc((size_t)NE * HD * FD * 2);

    hipMemsetAsync(counts, 0, NE * 4, stream);
    // weight convert+transpose: [E][K][N] f32 -> [E][N][K] bf16
    k_wt<<<dim3(FD / 64, HD / 64, NE), 256, 0, stream>>>(w1, w1t, HD, FD);
    k_wt<<<dim3(FD / 64, HD / 64, NE), 256, 0, stream>>>(w3, w3t, HD, FD);
    k_wt<<<dim3(HD / 64, FD / 64, NE), 256, 0, stream>>>(w2, w2t, FD, HD);
    k_cvt<<<(NTOK * HD) / (256 * 8), 256, 0, stream>>>(x, xb);
    k_router<<<NTOK / 4, 256, 0, stream>>>(x, gw, sel, selw, counts);
    k_scan<<<1, 64, 0, stream>>>(counts, basep, fillc);
    k_fill<<<NTOK / 256, 256, 0, stream>>>(sel, selw, basep, fillc, rowmap, rowk, roww);
    k_gemm1<<<dim3(FD / BN, NTOK / BM, NE), 256, 0, stream>>>(xb, w1t, w3t, counts, basep, rowmap, act);
    k_gemm2<<<dim3(HD / BN2, NTOK / BM, NE), 256, 0, stream>>>(act, w2t, counts, basep, rowmap, rowk, roww, partial);
    k_combine<<<(NTOK * HD) / (256 * 4), 256, 0, stream>>>(partial, out);
}